// Round 10
// baseline (1702.124 us; speedup 1.0000x reference)
//
#include <hip/hip_runtime.h>
#include <math.h>

#define SS   96
#define TM   96
#define BB   8
#define VV   32000
#define EE   256
#define HH   512
#define NTOK (SS + TM)     // 192
#define G4   (4 * HH)      // 2048
#define NEGF (-1e30f)
#define NSCAN 64           // scan blocks (r3 structure)
#define NHELP 192          // helper blocks
#define NGRID (NSCAN + NHELP)
#define NXT   768          // xih tiles (96 flat-tile x 8 row-blocks)
#define NCVT  8000         // Wread cvt chunks (2048 f32 each)
#define NTILE 500          // vocab column tiles (64 cols)
#define NPASS 12           // vocab row passes (64 rows)
#define NUNITS (NTILE * NPASS)

typedef __attribute__((ext_vector_type(8))) short short8;
typedef __attribute__((ext_vector_type(4))) float f32x4;
typedef __attribute__((ext_vector_type(4))) unsigned uint32x4;

// ---- workspace layout (float offsets) ----
#define XIH_OFF   ((size_t)0)
#define XIH_SZ    ((size_t)NTOK * BB * G4)       // 3,145,728 f
#define HALL_OFF  (XIH_OFF + XIH_SZ)
#define HALL_SZ   ((size_t)NTOK * BB * HH)       // 786,432 f
#define Q_OFF     (HALL_OFF + HALL_SZ)
#define Q_SZ      ((size_t)TM * BB * HH)         // 393,216 f
#define PPTR_OFF  (Q_OFF + Q_SZ)
#define ASENT_OFF (PPTR_OFF + (size_t)(TM * BB))
#define SSUM_OFF  (ASENT_OFF + (size_t)(TM * BB))
#define LSTAR_OFF (SSUM_OFF + (size_t)(TM * BB))
#define FLAG_OFF  (LSTAR_OFF + (size_t)(TM * BB))  // 64 block flags x 16 u32
#define XCNT_OFF  (FLAG_OFF + (size_t)1024)        // 12 group counters (pad 128)
#define WCNT_OFF  (XCNT_OFF + (size_t)128)         // 1 counter (pad 16)
#define ABF_OFF   (WCNT_OFF + (size_t)16)
#define ABF_SZF   ((size_t)(TM * BB) * HH / 2)     // 196,608 f
#define WBF_OFF   (ABF_OFF + ABF_SZF)
#define WBF_SZF   ((size_t)VV * HH / 2)            // 8,192,000 f

__device__ __forceinline__ float sigf(float x) { return 1.f / (1.f + __expf(-x)); }

__device__ __forceinline__ unsigned short f2bf(float x) {
    unsigned bits = __float_as_uint(x);
    bits += 0x7FFFu + ((bits >> 16) & 1u);   // RNE
    return (unsigned short)(bits >> 16);
}

// ============ MEGA kernel: scan (blocks 0..63) + helpers (64..255) ============
// Scan: round-3 structure verbatim (best measured k_lstm, f32 LDS dot, distributed
// flag barrier) + (a) gate on xih group counters (helpers produce xih), (b) inline
// Abf bf16 store for decoder steps, (c) final flag = 192.
// Helpers: xih tiles -> Wread bf16 cvt -> vocab MFMA units gated on scan progress.
// Coherence rule: every buffer WRITTEN in this kernel is written write-through
// (agent atomics / sc0 sc1) and read via L2-bypassing loads -> no cross-XCD L2
// coherence assumption. All spins wait on work that completes unconditionally.
__global__ void __launch_bounds__(256, 1)
k_mega(const int* __restrict__ src, const int* __restrict__ tgt,
       const float* __restrict__ emb, const float* __restrict__ Wih,
       const float* __restrict__ bih, const float* __restrict__ bhh,
       const float* __restrict__ Whh, const float* __restrict__ Wread,
       float* __restrict__ xih, float* __restrict__ hall,
       unsigned short* __restrict__ abf, unsigned short* __restrict__ wbf,
       unsigned* __restrict__ flags, unsigned* __restrict__ xcnt,
       unsigned* __restrict__ wcnt,
       float* __restrict__ ssum, float* __restrict__ lstar) {
    __shared__ float smem[8 * 516];   // scan: hb staging; helper: xih xs tile
    const int bx  = blockIdx.x;
    const int tid = threadIdx.x;

    if (bx < NSCAN) {
        // ================= SCAN (r3) =================
        const int gid  = bx * 256 + tid;
        const int b    = gid & 7;
        const int gate = (gid >> 3) & 3;     // 0=i 1=f 2=g 3=o
        const int i    = gid >> 5;
        const int row  = gate * HH + i;
        const float4* w4 = (const float4*)(Whh + (size_t)row * HH);
        const int l = tid & 63;

        // gate: xih group 0 ready (helpers write it unconditionally)
        if (tid == 0)
            while (__hip_atomic_load(&xcnt[0], __ATOMIC_RELAXED,
                                     __HIP_MEMORY_SCOPE_AGENT) < 64u) {}
        __syncthreads();

        float xnext;
        {
            const float* xp = xih + (size_t)(0 * BB + b) * G4 + row;
            asm volatile("global_load_dword %0, %1, off sc0 sc1"
                         : "=v"(xnext) : "v"(xp) : "memory");
        }
        float c = 0.f;

        for (int t = 0; t < NTOK; ++t) {
            if (t > 0) {
                // stage h_{t-1} from hall (agent loads = L3-fresh)
                const float* hprev = hall + (size_t)(t - 1) * (BB * HH);
                float tmp[16];
#pragma unroll
                for (int u = 0; u < 16; ++u)
                    tmp[u] = __hip_atomic_load(hprev + tid + u * 256,
                                               __ATOMIC_RELAXED, __HIP_MEMORY_SCOPE_AGENT);
#pragma unroll
                for (int u = 0; u < 16; ++u) {
                    int e = tid + u * 256;
                    smem[(e >> 9) * 516 + (e & 511)] = tmp[u];
                }
                __syncthreads();
            }

            asm volatile("s_waitcnt vmcnt(0)" ::: "memory");
            __builtin_amdgcn_sched_barrier(0);
            float acc = xnext;

            if (t > 0) {
                const float4* h4 = (const float4*)(smem + b * 516);
#pragma unroll 8
                for (int k4 = 0; k4 < HH / 4; ++k4) {
                    float4 w = w4[k4];
                    float4 h = h4[k4];
                    acc += w.x * h.x + w.y * h.y + w.z * h.z + w.w * h.w;
                }
            }
            float gf = __shfl_down(acc, 8, 64);
            float gg = __shfl_down(acc, 16, 64);
            float go = __shfl_down(acc, 24, 64);
            float hv = 0.f;
            if (gate == 0) {
                float is = sigf(acc);
                float fs = sigf(gf);
                float gv = tanhf(gg);
                float os = sigf(go);
                c = fs * c + is * gv;
                hv = os * tanhf(c);
                __hip_atomic_store(&hall[(size_t)(t * BB + b) * HH + i], hv,
                                   __ATOMIC_RELAXED, __HIP_MEMORY_SCOPE_AGENT);
            }
            if (t >= SS) {
                // inline Abf bf16: lanes 0..7 pack (own h, lane+32's h) -> cols i, i+1
                float hv2 = __shfl_down(hv, 32, 64);
                if (l < 8) {
                    unsigned pk = (unsigned)f2bf(hv) | ((unsigned)f2bf(hv2) << 16);
                    __hip_atomic_store(
                        (unsigned*)(abf + ((size_t)(t - SS) * BB + b) * HH + i), pk,
                        __ATOMIC_RELAXED, __HIP_MEMORY_SCOPE_AGENT);
                }
            }

            __syncthreads();   // drain all publishes (vmcnt0 before barrier)
            if (tid == 0)
                __hip_atomic_store(&flags[(size_t)bx * 16], (unsigned)(t + 1),
                                   __ATOMIC_RELAXED, __HIP_MEMORY_SCOPE_AGENT);

            if (t < NTOK - 1) {
                if (((t + 1) & 15) == 0 && tid == 0) {
                    // gate next 16-token xih group
                    while (__hip_atomic_load(&xcnt[(t + 1) >> 4], __ATOMIC_RELAXED,
                                             __HIP_MEMORY_SCOPE_AGENT) < 64u) {}
                }
                if (tid < 64)
                    while (__hip_atomic_load(&flags[(size_t)tid * 16], __ATOMIC_RELAXED,
                                             __HIP_MEMORY_SCOPE_AGENT) < (unsigned)(t + 1)) {}
                __syncthreads();
                const float* xp = xih + ((size_t)(t + 1) * BB + b) * G4 + row;
                asm volatile("global_load_dword %0, %1, off sc0 sc1"
                             : "=v"(xnext) : "v"(xp) : "memory");
            }
        }
        return;
    }

    // ================= HELPERS =================
    const int hid = bx - NSCAN;

    // ---- 1) xih tiles: flat tile n -> x = n>>3 (16 (t,b) entries), rb = n&7 ----
    for (int n = hid; n < NXT; n += NHELP) {
        const int x = n >> 3, rb = n & 7;
        const int tau0 = x * 16;
        const int row0 = rb * 256;
        for (int e = tid; e < 16 * EE; e += 256) {
            int tk = e >> 8, k = e & 255;
            int tau = tau0 + tk;
            int idx = (tau < SS * BB) ? src[tau] : tgt[tau - SS * BB];
            smem[tk * EE + k] = (idx == 0) ? 0.f : emb[(size_t)idx * EE + k];
        }
        __syncthreads();

        const int row = row0 + tid;
        const float bias = bih[row] + bhh[row];
        float acc[16];
#pragma unroll
        for (int r = 0; r < 16; ++r) acc[r] = bias;
        const float4* w4 = (const float4*)(Wih + (size_t)row * EE);
        for (int k4 = 0; k4 < EE / 4; ++k4) {
            float4 w = w4[k4];
#pragma unroll
            for (int r = 0; r < 16; ++r) {
                float4 xv = *((const float4*)&smem[r * EE + k4 * 4]);
                acc[r] += w.x * xv.x + w.y * xv.y + w.z * xv.z + w.w * xv.w;
            }
        }
#pragma unroll
        for (int r = 0; r < 16; ++r)
            __hip_atomic_store(&xih[(size_t)(tau0 + r) * G4 + row], acc[r],
                               __ATOMIC_RELAXED, __HIP_MEMORY_SCOPE_AGENT);
        __syncthreads();   // drains this block's write-through stores
        if (tid == 0)
            __hip_atomic_fetch_add(&xcnt[x >> 3], 1u,
                                   __ATOMIC_RELEASE, __HIP_MEMORY_SCOPE_AGENT);
        __syncthreads();   // smem reuse safety
    }

    // ---- 2) Wread -> bf16 (write-through) ----
    for (int cch = hid; cch < NCVT; cch += NHELP) {
        size_t base = (size_t)cch * 2048 + (size_t)tid * 8;
        float4 f0 = *(const float4*)(Wread + base);
        float4 f1 = *(const float4*)(Wread + base + 4);
        uint32x4 o;
        o.x = (unsigned)f2bf(f0.x) | ((unsigned)f2bf(f0.y) << 16);
        o.y = (unsigned)f2bf(f0.z) | ((unsigned)f2bf(f0.w) << 16);
        o.z = (unsigned)f2bf(f1.x) | ((unsigned)f2bf(f1.y) << 16);
        o.w = (unsigned)f2bf(f1.z) | ((unsigned)f2bf(f1.w) << 16);
        asm volatile("global_store_dwordx4 %0, %1, off sc0 sc1"
                     :: "v"(wbf + base), "v"(o) : "memory");
    }
    __syncthreads();   // drain cvt stores
    if (tid == 0) {
        __hip_atomic_fetch_add(wcnt, 1u, __ATOMIC_RELEASE, __HIP_MEMORY_SCOPE_AGENT);
        while (__hip_atomic_load(wcnt, __ATOMIC_RELAXED,
                                 __HIP_MEMORY_SCOPE_AGENT) < (unsigned)NHELP)
            __builtin_amdgcn_s_sleep(16);
    }
    __syncthreads();

    // ---- 3) vocab units (pass-major), gated on scan progress ----
    const int wv  = tid >> 6;
    const int l   = tid & 63;
    const int r16 = l & 15;
    const int kg  = l >> 4;
    union fragu { uint32x4 u4; short8 s; };
    int lastp = -1;

    for (int u = hid; u < NUNITS; u += NHELP) {
        const int p    = u / NTILE;
        const int tile = u - p * NTILE;
        if (p != lastp) {
            lastp = p;
            const unsigned tgtf = 104u + 8u * (unsigned)p;   // p=11 -> 192
            for (;;) {
                unsigned v = __hip_atomic_load(&flags[(size_t)l * 16],
                                               __ATOMIC_RELAXED, __HIP_MEMORY_SCOPE_AGENT);
                if (__all(v >= tgtf)) break;
                __builtin_amdgcn_s_sleep(16);
            }
        }
        const int n0    = tile * 64;
        const int row0p = p * 64 + wv * 16;

        fragu A[16];
        const unsigned short* arow = abf + (size_t)(row0p + r16) * HH + kg * 8;
#pragma unroll
        for (int ks = 0; ks < 16; ++ks)
            asm volatile("global_load_dwordx4 %0, %1, off sc0 sc1"
                         : "=v"(A[ks].u4) : "v"(arow + ks * 32) : "memory");

        f32x4 acc0 = {0.f,0.f,0.f,0.f}, acc1 = acc0, acc2 = acc0, acc3 = acc0;
#pragma unroll
        for (int cb = 0; cb < 4; ++cb) {
            fragu Bf[16];
            const unsigned short* brow = wbf + (size_t)(n0 + cb * 16 + r16) * HH + kg * 8;
#pragma unroll
            for (int ks = 0; ks < 16; ++ks)
                asm volatile("global_load_dwordx4 %0, %1, off sc0 sc1"
                             : "=v"(Bf[ks].u4) : "v"(brow + ks * 32) : "memory");
            asm volatile("s_waitcnt vmcnt(0)" ::: "memory");
            __builtin_amdgcn_sched_barrier(0);
#pragma unroll
            for (int ks = 0; ks < 16; ++ks) {
                f32x4 t0 = (cb == 0) ? acc0 : (cb == 1) ? acc1 : (cb == 2) ? acc2 : acc3;
                t0 = __builtin_amdgcn_mfma_f32_16x16x32_bf16(A[ks].s, Bf[ks].s, t0, 0, 0, 0);
                if (cb == 0) acc0 = t0; else if (cb == 1) acc1 = t0;
                else if (cb == 2) acc2 = t0; else acc3 = t0;
            }
        }

#pragma unroll
        for (int reg = 0; reg < 4; ++reg) {
            const int rowg = row0p + 4 * kg + reg;
            const int vsx  = tgt[BB + rowg];
            int cg;
            cg = n0 +  0 + r16; if (cg == vsx) lstar[rowg] = acc0[reg];
            cg = n0 + 16 + r16; if (cg == vsx) lstar[rowg] = acc1[reg];
            cg = n0 + 32 + r16; if (cg == vsx) lstar[rowg] = acc2[reg];
            cg = n0 + 48 + r16; if (cg == vsx) lstar[rowg] = acc3[reg];

            float v = __expf(acc0[reg]) + __expf(acc1[reg]) +
                      __expf(acc2[reg]) + __expf(acc3[reg]);
            v += __shfl_xor(v, 1, 64);
            v += __shfl_xor(v, 2, 64);
            v += __shfl_xor(v, 4, 64);
            v += __shfl_xor(v, 8, 64);
            if (r16 == 0) atomicAdd(&ssum[rowg], v);
        }
    }
}

// ============ Kernel 3: Q = tanh(Hdec @ W_att^T). grid TM, block 256 ============
__global__ void __launch_bounds__(256) k_q(const float* __restrict__ hall,
                                           const float* __restrict__ Watt,
                                           float* __restrict__ q) {
    __shared__ float hb[8 * 516];
    const int t = blockIdx.x, tid = threadIdx.x;
    const float* hdec = hall + (size_t)(SS + t) * (BB * HH);
    for (int e = tid; e < BB * HH; e += 256)
        hb[(e >> 9) * 516 + (e & 511)] = hdec[e];
    __syncthreads();

    for (int oi = tid; oi < BB * HH; oi += 256) {
        int b = oi & 7, ii = oi >> 3;
        const float4* w4 = (const float4*)(Watt + (size_t)ii * HH);
        const float4* h4 = (const float4*)(hb + b * 516);
        float acc = 0.f;
        for (int k4 = 0; k4 < HH / 4; ++k4) {
            float4 w = w4[k4], h = h4[k4];
            acc += w.x * h.x + w.y * h.y + w.z * h.z + w.w * h.w;
        }
        q[(size_t)(t * BB + b) * HH + ii] = tanhf(acc);
    }
}

// ============ Kernel 4: attention scores + softmax + pointer gather ============
__global__ void __launch_bounds__(256) k_att(const float* __restrict__ hall,
                                             const float* __restrict__ q,
                                             const float* __restrict__ sent,
                                             const int* __restrict__ src,
                                             const int* __restrict__ tgt,
                                             float* __restrict__ pptr,
                                             float* __restrict__ asent) {
    __shared__ float qs[HH];
    __shared__ float av[256];
    __shared__ float red[256];
    const int t = blockIdx.x, b = blockIdx.y, tid = threadIdx.x;

    for (int e = tid; e < HH; e += 256) qs[e] = q[(size_t)(t * BB + b) * HH + e];
    __syncthreads();

    const int j = tid;
    float acc = NEGF;
    if (j < SS + TM + 1) {
        bool valid = (j < SS + t + 1) || (j == SS + TM);
        if (valid) {
            const float* vptr = (j < SS + TM) ? (hall + (size_t)(j * BB + b) * HH) : sent;
            const float4* v4 = (const float4*)vptr;
            const float4* q4 = (const float4*)qs;
            float a = 0.f;
            for (int k4 = 0; k4 < HH / 4; ++k4) {
                float4 v = v4[k4], qq = q4[k4];
                a += v.x * qq.x + v.y * qq.y + v.z * qq.z + v.w * qq.w;
            }
            acc = a;
        }
    }
    red[tid] = acc;
    __syncthreads();
    for (int s2 = 128; s2 > 0; s2 >>= 1) {
        if (tid < s2) red[tid] = fmaxf(red[tid], red[tid + s2]);
        __syncthreads();
    }
    float m = red[0];
    __syncthreads();
    float e = __expf(acc - m);
    red[tid] = e;
    __syncthreads();
    for (int s2 = 128; s2 > 0; s2 >>= 1) {
        if (tid < s2) red[tid] += red[tid + s2];
        __syncthreads();
    }
    float denom = red[0];
    __syncthreads();
    float a = e / denom;
    av[tid] = a;
    __syncthreads();

    const int vs = tgt[(t + 1) * BB + b];
    float contrib = 0.f;
    if (j < SS) {
        if (src[j * BB + b] == vs) contrib += av[j];        // a_src
        if (tgt[j * BB + b] == vs) contrib += av[SS + j];   // a_tgt
    }
    red[tid] = contrib;
    __syncthreads();
    for (int s2 = 128; s2 > 0; s2 >>= 1) {
        if (tid < s2) red[tid] += red[tid + s2];
        __syncthreads();
    }
    if (tid == 0) {
        pptr[t * BB + b]  = red[0];
        asent[t * BB + b] = av[SS + TM];
    }
}

// ============ Kernel 6: gold log-likelihoods + per-batch sums ============
__global__ void __launch_bounds__(768) k_final(const float* __restrict__ pptr,
                                               const float* __restrict__ asent,
                                               const float* __restrict__ ssum,
                                               const float* __restrict__ lstar,
                                               const int* __restrict__ tgt,
                                               float* __restrict__ out) {
    __shared__ float g[TM * BB], gp[TM * BB];
    const int tid = threadIdx.x;          // = t*8+b
    const int vs = tgt[tid + BB];
    const float pv = __expf(lstar[tid]) / ssum[tid];
    const float ps = pptr[tid];
    const float as = asent[tid];
    if (vs != 0) {
        g[tid]  = logf(ps + pv * as);
        gp[tid] = logf(ps + as);
    } else {
        g[tid] = 0.f; gp[tid] = 0.f;
    }
    __syncthreads();
    if (tid < BB) {
        float s1 = 0.f, s2 = 0.f;
        for (int t = 0; t < TM; ++t) { s1 += g[t * BB + tid]; s2 += gp[t * BB + tid]; }
        out[tid] = s1;
        out[BB + tid] = s2;
    }
}

extern "C" void kernel_launch(void* const* d_in, const int* in_sizes, int n_in,
                              void* d_out, int out_size, void* d_ws, size_t ws_size,
                              hipStream_t stream) {
    (void)in_sizes; (void)n_in; (void)out_size; (void)ws_size;
    const int*   src   = (const int*)d_in[0];
    const int*   tgt   = (const int*)d_in[1];
    const float* emb   = (const float*)d_in[2];
    const float* Wih   = (const float*)d_in[3];
    const float* Whh   = (const float*)d_in[4];
    const float* bih   = (const float*)d_in[5];
    const float* bhh   = (const float*)d_in[6];
    const float* Watt  = (const float*)d_in[7];
    const float* sent  = (const float*)d_in[8];
    const float* Wread = (const float*)d_in[9];
    float* ws  = (float*)d_ws;
    float* out = (float*)d_out;

    // zero SSUM + LSTAR + FLAGS + XCNT + WCNT (contiguous: 768+768+1024+128+16)
    (void)hipMemsetAsync((void*)(ws + SSUM_OFF), 0, (size_t)2704 * sizeof(float), stream);

    {
        float* xihp = ws + XIH_OFF;
        float* hallp = ws + HALL_OFF;
        unsigned short* abf = (unsigned short*)(ws + ABF_OFF);
        unsigned short* wbf = (unsigned short*)(ws + WBF_OFF);
        unsigned* flags = (unsigned*)(ws + FLAG_OFF);
        unsigned* xcnt  = (unsigned*)(ws + XCNT_OFF);
        unsigned* wcnt  = (unsigned*)(ws + WCNT_OFF);
        float* ssum  = ws + SSUM_OFF;
        float* lstar = ws + LSTAR_OFF;
        void* args[] = { (void*)&src, (void*)&tgt, (void*)&emb, (void*)&Wih,
                         (void*)&bih, (void*)&bhh, (void*)&Whh, (void*)&Wread,
                         (void*)&xihp, (void*)&hallp, (void*)&abf, (void*)&wbf,
                         (void*)&flags, (void*)&xcnt, (void*)&wcnt,
                         (void*)&ssum, (void*)&lstar };
        (void)hipLaunchCooperativeKernel((void*)k_mega, dim3(NGRID), dim3(256),
                                         args, 0, stream);
    }

    k_q<<<dim3(TM), 256, 0, stream>>>(ws + HALL_OFF, Watt, ws + Q_OFF);

    k_att<<<dim3(TM, BB), 256, 0, stream>>>(ws + HALL_OFF, ws + Q_OFF, sent,
                                            src, tgt, ws + PPTR_OFF, ws + ASENT_OFF);

    k_final<<<dim3(1), dim3(TM * BB), 0, stream>>>(ws + PPTR_OFF, ws + ASENT_OFF,
                                                   ws + SSUM_OFF, ws + LSTAR_OFF,
                                                   tgt, out);
}

// Round 11
// 1338.864 us; speedup vs baseline: 1.2713x; 1.2713x over previous
//
#include <hip/hip_runtime.h>
#include <math.h>

#define SS   96
#define TM   96
#define BB   8
#define VV   32000
#define EE   256
#define HH   512
#define NTOK (SS + TM)     // 192
#define G4   (4 * HH)      // 2048
#define NEGF (-1e30f)
#define LBLK 16            // k_lstm blocks

typedef __attribute__((ext_vector_type(8))) short short8;
typedef __attribute__((ext_vector_type(4))) float f32x4;
typedef __attribute__((ext_vector_type(4))) unsigned uint32x4;
typedef unsigned long long u64;

// ---- workspace layout (float offsets) ----
#define XIH_OFF   ((size_t)0)
#define XIH_SZ    ((size_t)NTOK * BB * G4)       // 3,145,728 f
#define HALL_OFF  (XIH_OFF + XIH_SZ)
#define HALL_SZ   ((size_t)NTOK * BB * HH)       // 786,432 f
#define Q_OFF     (HALL_OFF + HALL_SZ)
#define Q_SZ      ((size_t)TM * BB * HH)         // 393,216 f
#define PPTR_OFF  (Q_OFF + Q_SZ)
#define ASENT_OFF (PPTR_OFF + (size_t)(TM * BB))
#define SSUM_OFF  (ASENT_OFF + (size_t)(TM * BB))
#define LSTAR_OFF (SSUM_OFF + (size_t)(TM * BB))
#define FLAG_OFF  (LSTAR_OFF + (size_t)(TM * BB))   // 16 block flags x 16 u32 (pad 1024)
#define HBF_OFF   (FLAG_OFF + (size_t)1024)
#define HBF_SZF   ((size_t)2 * BB * HH / 2)         // 4,096 f (2 x 8 x 512 bf16)
#define WHHBF_OFF (HBF_OFF + HBF_SZF)
#define WHHBF_SZF ((size_t)G4 * HH / 2)             // 524,288 f
#define ABF_OFF   (WHHBF_OFF + WHHBF_SZF)
#define ABF_SZF   ((size_t)(TM * BB) * HH / 2)      // 196,608 f
#define WBF_OFF   (ABF_OFF + ABF_SZF)
#define WBF_SZF   ((size_t)VV * HH / 2)             // 8,192,000 f
#define NEED_F    (WBF_OFF + WBF_SZF)

__device__ __forceinline__ float sigf(float x) { return 1.f / (1.f + __expf(-x)); }

__device__ __forceinline__ unsigned short f2bf(float x) {
    unsigned bits = __float_as_uint(x);
    bits += 0x7FFFu + ((bits >> 16) & 1u);   // RNE
    return (unsigned short)(bits >> 16);
}

// ============ Kernel 1: Xih[tok][row] = emb_eff[idx[tok]] . W_ih[row] + bias ============
__global__ void __launch_bounds__(256) k_xih(const int* __restrict__ src,
                                             const int* __restrict__ tgt,
                                             const float* __restrict__ emb,
                                             const float* __restrict__ Wih,
                                             const float* __restrict__ bih,
                                             const float* __restrict__ bhh,
                                             float* __restrict__ xih) {
    __shared__ float xs[16][EE];   // 16 KB
    const int tok0 = blockIdx.x * 16;
    const int row0 = blockIdx.y * 256;
    const int tid  = threadIdx.x;

    for (int e = tid; e < 16 * EE; e += 256) {
        int tk = e >> 8, k = e & 255;
        int tau = tok0 + tk;
        int idx = (tau < SS * BB) ? src[tau] : tgt[tau - SS * BB];
        xs[tk][k] = (idx == 0) ? 0.f : emb[(size_t)idx * EE + k];   // PAD row zeroed
    }
    __syncthreads();

    const int row = row0 + tid;
    const float bias = bih[row] + bhh[row];
    float acc[16];
#pragma unroll
    for (int r = 0; r < 16; ++r) acc[r] = bias;

    const float4* w4 = (const float4*)(Wih + (size_t)row * EE);
    for (int k4 = 0; k4 < EE / 4; ++k4) {
        float4 w = w4[k4];
#pragma unroll
        for (int r = 0; r < 16; ++r) {
            float4 x = *((const float4*)&xs[r][k4 * 4]);
            acc[r] += w.x * x.x + w.y * x.y + w.z * x.z + w.w * x.w;
        }
    }
#pragma unroll
    for (int r = 0; r < 16; ++r)
        xih[(size_t)(tok0 + r) * G4 + row] = acc[r];
}

// ============ generic f32 -> bf16 converter (8 elems/thread) ============
__global__ void __launch_bounds__(256) k_cvt2(const float* __restrict__ src,
                                              unsigned short* __restrict__ dst,
                                              long n) {
    size_t base = ((size_t)blockIdx.x * 256 + threadIdx.x) * 8;
    if ((long)base >= n) return;
    float4 f0 = *(const float4*)(src + base);
    float4 f1 = *(const float4*)(src + base + 4);
    uint4 o;
    o.x = (unsigned)f2bf(f0.x) | ((unsigned)f2bf(f0.y) << 16);
    o.y = (unsigned)f2bf(f0.z) | ((unsigned)f2bf(f0.w) << 16);
    o.z = (unsigned)f2bf(f1.x) | ((unsigned)f2bf(f1.y) << 16);
    o.w = (unsigned)f2bf(f1.z) | ((unsigned)f2bf(f1.w) << 16);
    *(uint4*)(dst + base) = o;
}

// ============ Kernel 2: LSTM scan — LDS weights (r9-verified) + r3 flag sync ============
// 16 blocks x 256 thr. Wave wv: gate-rows I0 = bx*32 + wv*8 (x4 gates).
// A (Whh bf16) staged ONCE into 128 KB LDS in fragment layout; per-step A access =
// conflict-free ds_read_b128 (r9-verified numerically).
// Sync per step (r3-proven): publish h (single dbuf copy, sc0 sc1 write-through) ->
// per-wave vmcnt(0) drain -> syncthreads -> tid0 raises block flag -> consumers'
// lanes l<16 poll the 16 flags in parallel, then batched sc0 sc1 B loads with ONE
// vmcnt(0). Placement-independent (all cross-block traffic device-coherent).
// Inline abf (bf16 decoder h) store for t>=SS (r10-verified) kills the Abf cvt pass.
__global__ void __launch_bounds__(256, 1) k_lstm(const float* __restrict__ xih,
                                                 const unsigned short* __restrict__ whhbf,
                                                 float* __restrict__ hall,
                                                 unsigned short* __restrict__ hbf,
                                                 unsigned short* __restrict__ abf,
                                                 unsigned* __restrict__ flags) {
    extern __shared__ short lA[];   // 131072 B
    const int tid = threadIdx.x;
    const int wv  = tid >> 6;
    const int l   = tid & 63;
    const int b16 = l & 15;          // MFMA col = batch (cols 8..15 don't-care)
    const int kg  = l >> 4;          // 0..3
    const int bb  = b16 & 7;         // clamp for pad-col loads
    const int bx  = blockIdx.x;
    const int I0  = bx * 32 + wv * 8;

    // ---- stage A fragments into LDS (once; r9 layout, verified) ----
    const int j = b16;
    const unsigned short* a0p = whhbf + ((size_t)((j >> 3) * HH + I0 + (j & 7))) * HH + kg * 8;
    const unsigned short* a1p = whhbf + ((size_t)((2 + (j >> 3)) * HH + I0 + (j & 7))) * HH + kg * 8;
    short* lA0 = lA + (((size_t)wv * 2 + 0) * 16 * 64 + l) * 8;
    short* lA1 = lA + (((size_t)wv * 2 + 1) * 16 * 64 + l) * 8;
#pragma unroll
    for (int ks = 0; ks < 16; ++ks) {
        *(short8*)(lA0 + ks * 512) = *(const short8*)(a0p + ks * 32);
        *(short8*)(lA1 + ks * 512) = *(const short8*)(a1p + ks * 32);
    }
    __syncthreads();

    // xih C-init addressing: lane (kg, reg r): D row16 = 4*kg+r
    const int xgate0 = (kg >> 1);        // 0:i 1:f
    const int xgate1 = 2 + (kg >> 1);    // 2:g 3:o
    const int xi     = I0 + (kg & 1) * 4;

    float c0[4] = {0.f, 0.f, 0.f, 0.f};
    union fragu { uint32x4 u4; short8 s; };

    for (int t = 0; t < NTOK; ++t) {
        // issue xih loads early (plain cached; resolve under the poll)
        const float* xb = xih + ((size_t)t * BB + bb) * G4;
        float4 x0 = *(const float4*)(xb + xgate0 * HH + xi);
        float4 x1 = *(const float4*)(xb + xgate1 * HH + xi);

        fragu Bf[16];
        if (t > 0) {
            // poll the 16 block flags (lane l < 16 polls flag l)
            if (l < 16) {
                while (__hip_atomic_load(&flags[(size_t)l * 16], __ATOMIC_RELAXED,
                                         __HIP_MEMORY_SCOPE_AGENT) < (unsigned)t) {}
            }
            // batched B loads (h_{t-1}, parity (t-1)&1), one wait for all 16
            const unsigned short* hsrc =
                hbf + ((t - 1) & 1) * (BB * HH) + (size_t)bb * HH + kg * 8;
#pragma unroll
            for (int ks = 0; ks < 16; ++ks)
                asm volatile("global_load_dwordx4 %0, %1, off sc0 sc1"
                             : "=v"(Bf[ks].u4) : "v"(hsrc + ks * 32) : "memory");
            asm volatile("s_waitcnt vmcnt(0)" ::: "memory");
            __builtin_amdgcn_sched_barrier(0);
        }

        f32x4 acc0 = {x0.x, x0.y, x0.z, x0.w};
        f32x4 acc1 = {x1.x, x1.y, x1.z, x1.w};
        if (t > 0) {
#pragma unroll
            for (int ks = 0; ks < 16; ++ks) {
                short8 a0 = *(const short8*)(lA0 + ks * 512);
                short8 a1 = *(const short8*)(lA1 + ks * 512);
                acc0 = __builtin_amdgcn_mfma_f32_16x16x32_bf16(a0, Bf[ks].s, acc0, 0, 0, 0);
                acc1 = __builtin_amdgcn_mfma_f32_16x16x32_bf16(a1, Bf[ks].s, acc1, 0, 0, 0);
            }
        }

        // activations: lanes l<32 hold i (acc0) / g (acc1); f/o at lane+32
        float hreg[4];
#pragma unroll
        for (int r = 0; r < 4; ++r) {
            float gf = __shfl_down(acc0[r], 32, 64);
            float go = __shfl_down(acc1[r], 32, 64);
            float is = sigf(acc0[r]);
            float fs = sigf(gf);
            float gv = tanhf(acc1[r]);
            float os = sigf(go);
            c0[r] = fs * c0[r] + is * gv;
            hreg[r] = os * tanhf(c0[r]);
        }

        if (l < 32 && b16 < BB) {
            const int ib = I0 + kg * 4;   // kg in {0,1}
            // f32 h for downstream kernels (plain; flushed at kernel end)
            *(float4*)(hall + ((size_t)t * BB + b16) * HH + ib) =
                make_float4(hreg[0], hreg[1], hreg[2], hreg[3]);
            u64 pk = (u64)f2bf(hreg[0]) | ((u64)f2bf(hreg[1]) << 16) |
                     ((u64)f2bf(hreg[2]) << 32) | ((u64)f2bf(hreg[3]) << 48);
            if (t >= SS)   // decoder h in bf16 for k_vocab (plain; flushed at end)
                *(u64*)(abf + ((size_t)(t - SS) * BB + b16) * HH + ib) = pk;
            if (t < NTOK - 1) {
                // bf16 h publish (device-coherent write-through)
                unsigned short* hdst = hbf + (t & 1) * (BB * HH) + (size_t)b16 * HH + ib;
                asm volatile("global_store_dwordx2 %0, %1, off sc0 sc1"
                             :: "v"(hdst), "v"(pk) : "memory");
            }
        }

        if (t < NTOK - 1) {
            // per-wave drain of publishes, block-wide order, raise this block's flag
            asm volatile("s_waitcnt vmcnt(0)" ::: "memory");
            __syncthreads();
            if (tid == 0)
                __hip_atomic_store(&flags[(size_t)bx * 16], (unsigned)(t + 1),
                                   __ATOMIC_RELAXED, __HIP_MEMORY_SCOPE_AGENT);
        }
    }
}

// ============ Kernel 3: Q = tanh(Hdec @ W_att^T). grid TM, block 256 ============
__global__ void __launch_bounds__(256) k_q(const float* __restrict__ hall,
                                           const float* __restrict__ Watt,
                                           float* __restrict__ q) {
    __shared__ float hb[8 * 516];
    const int t = blockIdx.x, tid = threadIdx.x;
    const float* hdec = hall + (size_t)(SS + t) * (BB * HH);
    for (int e = tid; e < BB * HH; e += 256)
        hb[(e >> 9) * 516 + (e & 511)] = hdec[e];
    __syncthreads();

    for (int oi = tid; oi < BB * HH; oi += 256) {
        int b = oi & 7, ii = oi >> 3;
        const float4* w4 = (const float4*)(Watt + (size_t)ii * HH);
        const float4* h4 = (const float4*)(hb + b * 516);
        float acc = 0.f;
        for (int k4 = 0; k4 < HH / 4; ++k4) {
            float4 w = w4[k4], h = h4[k4];
            acc += w.x * h.x + w.y * h.y + w.z * h.z + w.w * h.w;
        }
        q[(size_t)(t * BB + b) * HH + ii] = tanhf(acc);
    }
}

// ============ Kernel 4: attention scores + softmax + pointer gather ============
__global__ void __launch_bounds__(256) k_att(const float* __restrict__ hall,
                                             const float* __restrict__ q,
                                             const float* __restrict__ sent,
                                             const int* __restrict__ src,
                                             const int* __restrict__ tgt,
                                             float* __restrict__ pptr,
                                             float* __restrict__ asent) {
    __shared__ float qs[HH];
    __shared__ float av[256];
    __shared__ float red[256];
    const int t = blockIdx.x, b = blockIdx.y, tid = threadIdx.x;

    for (int e = tid; e < HH; e += 256) qs[e] = q[(size_t)(t * BB + b) * HH + e];
    __syncthreads();

    const int j = tid;
    float acc = NEGF;
    if (j < SS + TM + 1) {
        bool valid = (j < SS + t + 1) || (j == SS + TM);
        if (valid) {
            const float* vptr = (j < SS + TM) ? (hall + (size_t)(j * BB + b) * HH) : sent;
            const float4* v4 = (const float4*)vptr;
            const float4* q4 = (const float4*)qs;
            float a = 0.f;
            for (int k4 = 0; k4 < HH / 4; ++k4) {
                float4 v = v4[k4], qq = q4[k4];
                a += v.x * qq.x + v.y * qq.y + v.z * qq.z + v.w * qq.w;
            }
            acc = a;
        }
    }
    red[tid] = acc;
    __syncthreads();
    for (int s2 = 128; s2 > 0; s2 >>= 1) {
        if (tid < s2) red[tid] = fmaxf(red[tid], red[tid + s2]);
        __syncthreads();
    }
    float m = red[0];
    __syncthreads();
    float e = __expf(acc - m);
    red[tid] = e;
    __syncthreads();
    for (int s2 = 128; s2 > 0; s2 >>= 1) {
        if (tid < s2) red[tid] += red[tid + s2];
        __syncthreads();
    }
    float denom = red[0];
    __syncthreads();
    float a = e / denom;
    av[tid] = a;
    __syncthreads();

    const int vs = tgt[(t + 1) * BB + b];
    float contrib = 0.f;
    if (j < SS) {
        if (src[j * BB + b] == vs) contrib += av[j];        // a_src
        if (tgt[j * BB + b] == vs) contrib += av[SS + j];   // a_tgt
    }
    red[tid] = contrib;
    __syncthreads();
    for (int s2 = 128; s2 > 0; s2 >>= 1) {
        if (tid < s2) red[tid] += red[tid + s2];
        __syncthreads();
    }
    if (tid == 0) {
        pptr[t * BB + b]  = red[0];
        asent[t * BB + b] = av[SS + TM];
    }
}

// ============ Kernel 5: vocab softmax stats via bf16 MFMA ============
__global__ void __launch_bounds__(256) k_vocab_mfma(const unsigned short* __restrict__ Abf,
                                                    const unsigned short* __restrict__ Wbf,
                                                    const int* __restrict__ tgt,
                                                    float* __restrict__ ssum,
                                                    float* __restrict__ lstar) {
    const int tid  = threadIdx.x;
    const int wave = tid >> 6;
    const int lane = tid & 63;
    const int r16  = lane & 15;
    const int kg   = lane >> 4;          // 0..3
    const int n0   = blockIdx.x * 64;

    const unsigned short* b0 = Wbf + (size_t)(n0 +  0 + r16) * HH + kg * 8;
    const unsigned short* b1 = Wbf + (size_t)(n0 + 16 + r16) * HH + kg * 8;
    const unsigned short* b2 = Wbf + (size_t)(n0 + 32 + r16) * HH + kg * 8;
    const unsigned short* b3 = Wbf + (size_t)(n0 + 48 + r16) * HH + kg * 8;

    for (int pass = 0; pass < 12; ++pass) {
        const int row0 = pass * 64 + wave * 16;
        const unsigned short* arow = Abf + (size_t)(row0 + r16) * HH + kg * 8;

        f32x4 acc0 = {0.f,0.f,0.f,0.f}, acc1 = acc0, acc2 = acc0, acc3 = acc0;
#pragma unroll
        for (int ks = 0; ks < 16; ++ks) {
            short8 a = *(const short8*)(arow + ks * 32);
            acc0 = __builtin_amdgcn_mfma_f32_16x16x32_bf16(a, *(const short8*)(b0 + ks * 32), acc0, 0, 0, 0);
            acc1 = __builtin_amdgcn_mfma_f32_16x16x32_bf16(a, *(const short8*)(b1 + ks * 32), acc1, 0, 0, 0);
            acc2 = __builtin_amdgcn_mfma_f32_16x16x32_bf16(a, *(const short8*)(b2 + ks * 32), acc2, 0, 0, 0);
            acc3 = __builtin_amdgcn_mfma_f32_16x16x32_bf16(a, *(const short8*)(b3 + ks * 32), acc3, 0, 0, 0);
        }

#pragma unroll
        for (int reg = 0; reg < 4; ++reg) {
            const int rowg = row0 + 4 * kg + reg;
            const int vs = tgt[BB + rowg];
            int cg;
            cg = n0 +  0 + r16; if (cg == vs) lstar[rowg] = acc0[reg];
            cg = n0 + 16 + r16; if (cg == vs) lstar[rowg] = acc1[reg];
            cg = n0 + 32 + r16; if (cg == vs) lstar[rowg] = acc2[reg];
            cg = n0 + 48 + r16; if (cg == vs) lstar[rowg] = acc3[reg];

            float v = __expf(acc0[reg]) + __expf(acc1[reg]) +
                      __expf(acc2[reg]) + __expf(acc3[reg]);
            v += __shfl_xor(v, 1, 64);
            v += __shfl_xor(v, 2, 64);
            v += __shfl_xor(v, 4, 64);
            v += __shfl_xor(v, 8, 64);
            if (r16 == 0) atomicAdd(&ssum[rowg], v);
        }
    }
}

// ============ Kernel 5-fallback: f32 vocab stats (used if ws too small) ============
__global__ void __launch_bounds__(256) k_vocab_f32(const float* __restrict__ hall,
                                                   const float* __restrict__ Wread,
                                                   const int* __restrict__ tgt,
                                                   float* __restrict__ ssum,
                                                   float* __restrict__ lstar) {
    __shared__ float hs[32 * HH];   // 64 KB
    const int tid = threadIdx.x;
    const int v0 = blockIdx.x * 512 + tid * 2;
    const int v1 = v0 + 1;
    const bool g0 = v0 < VV, g1 = v1 < VV;
    const float4* w40 = (const float4*)(Wread + (size_t)(g0 ? v0 : 0) * HH);
    const float4* w41 = (const float4*)(Wread + (size_t)(g1 ? v1 : 0) * HH);
    const int rbase0 = blockIdx.y * 128;

    for (int ch = 0; ch < 4; ++ch) {
        const int rbase = rbase0 + ch * 32;
        const float4* sp4 = (const float4*)(hall + ((size_t)SS * BB + rbase) * HH);
        float4* hs4 = (float4*)hs;
        for (int e = tid; e < 32 * HH / 4; e += 256) hs4[e] = sp4[e];
        __syncthreads();

        float acc0[32], acc1[32];
#pragma unroll
        for (int r = 0; r < 32; ++r) { acc0[r] = 0.f; acc1[r] = 0.f; }

        for (int k4 = 0; k4 < HH / 4; ++k4) {
            float4 w0 = w40[k4];
            float4 w1 = w41[k4];
#pragma unroll
            for (int r = 0; r < 32; ++r) {
                float4 h = *((const float4*)(hs + r * HH + k4 * 4));
                acc0[r] += w0.x * h.x + w0.y * h.y + w0.z * h.z + w0.w * h.w;
                acc1[r] += w1.x * h.x + w1.y * h.y + w1.z * h.z + w1.w * h.w;
            }
        }

#pragma unroll
        for (int r = 0; r < 32; ++r) {
            const int row = rbase + r;
            float val = 0.f;
            if (g0) val += __expf(acc0[r]);
            if (g1) val += __expf(acc1[r]);
#pragma unroll
            for (int d = 32; d > 0; d >>= 1) val += __shfl_xor(val, d, 64);
            if ((tid & 63) == 0) atomicAdd(&ssum[row], val);
            const int vs = tgt[row + BB];
            if (g0 && v0 == vs) lstar[row] = acc0[r];
            else if (g1 && v1 == vs) lstar[row] = acc1[r];
        }
        __syncthreads();
    }
}

// ============ Kernel 6: gold log-likelihoods + per-batch sums ============
__global__ void __launch_bounds__(768) k_final(const float* __restrict__ pptr,
                                               const float* __restrict__ asent,
                                               const float* __restrict__ ssum,
                                               const float* __restrict__ lstar,
                                               const int* __restrict__ tgt,
                                               float* __restrict__ out) {
    __shared__ float g[TM * BB], gp[TM * BB];
    const int tid = threadIdx.x;          // = t*8+b
    const int vs = tgt[tid + BB];
    const float pv = __expf(lstar[tid]) / ssum[tid];
    const float ps = pptr[tid];
    const float as = asent[tid];
    if (vs != 0) {
        g[tid]  = logf(ps + pv * as);
        gp[tid] = logf(ps + as);
    } else {
        g[tid] = 0.f; gp[tid] = 0.f;
    }
    __syncthreads();
    if (tid < BB) {
        float s1 = 0.f, s2 = 0.f;
        for (int t = 0; t < TM; ++t) { s1 += g[t * BB + tid]; s2 += gp[t * BB + tid]; }
        out[tid] = s1;
        out[BB + tid] = s2;
    }
}

extern "C" void kernel_launch(void* const* d_in, const int* in_sizes, int n_in,
                              void* d_out, int out_size, void* d_ws, size_t ws_size,
                              hipStream_t stream) {
    (void)in_sizes; (void)n_in; (void)out_size;
    const int*   src   = (const int*)d_in[0];
    const int*   tgt   = (const int*)d_in[1];
    const float* emb   = (const float*)d_in[2];
    const float* Wih   = (const float*)d_in[3];
    const float* Whh   = (const float*)d_in[4];
    const float* bih   = (const float*)d_in[5];
    const float* bhh   = (const float*)d_in[6];
    const float* Watt  = (const float*)d_in[7];
    const float* sent  = (const float*)d_in[8];
    const float* Wread = (const float*)d_in[9];
    float* ws  = (float*)d_ws;
    float* out = (float*)d_out;

    const bool use_mfma_vocab = ws_size >= NEED_F * sizeof(float);

    // zero SSUM + LSTAR + FLAGS (contiguous: 768+768+1024)
    (void)hipMemsetAsync((void*)(ws + SSUM_OFF), 0, (size_t)2560 * sizeof(float), stream);

    k_xih<<<dim3(NTOK * BB / 16, G4 / 256), 256, 0, stream>>>(
        src, tgt, emb, Wih, bih, bhh, ws + XIH_OFF);

    // Whh -> bf16 (needed by k_lstm)
    k_cvt2<<<dim3((unsigned)((size_t)G4 * HH / 8 / 256)), 256, 0, stream>>>(
        Whh, (unsigned short*)(ws + WHHBF_OFF), (long)G4 * HH);

    {
        const float* xih = ws + XIH_OFF;
        const unsigned short* whhbf = (const unsigned short*)(ws + WHHBF_OFF);
        float* hall = ws + HALL_OFF;
        unsigned short* hbf = (unsigned short*)(ws + HBF_OFF);
        unsigned short* abf = (unsigned short*)(ws + ABF_OFF);
        unsigned* flags = (unsigned*)(ws + FLAG_OFF);
        void* args[] = { (void*)&xih, (void*)&whhbf, (void*)&hall,
                         (void*)&hbf, (void*)&abf, (void*)&flags };
        (void)hipLaunchCooperativeKernel((void*)k_lstm, dim3(LBLK), dim3(256), args,
                                         131072, stream);
    }

    k_q<<<dim3(TM), 256, 0, stream>>>(ws + HALL_OFF, Watt, ws + Q_OFF);

    k_att<<<dim3(TM, BB), 256, 0, stream>>>(ws + HALL_OFF, ws + Q_OFF, sent,
                                            src, tgt, ws + PPTR_OFF, ws + ASENT_OFF);

    if (use_mfma_vocab) {
        k_cvt2<<<dim3((unsigned)((size_t)VV * HH / 8 / 256)), 256, 0, stream>>>(
            Wread, (unsigned short*)(ws + WBF_OFF), (long)VV * HH);
        k_vocab_mfma<<<dim3(VV / 64), 256, 0, stream>>>(
            (const unsigned short*)(ws + ABF_OFF),
            (const unsigned short*)(ws + WBF_OFF),
            tgt, ws + SSUM_OFF, ws + LSTAR_OFF);
    } else {
        k_vocab_f32<<<dim3(63, 6), 256, 0, stream>>>(ws + HALL_OFF, Wread, tgt,
                                                     ws + SSUM_OFF, ws + LSTAR_OFF);
    }

    k_final<<<dim3(1), dim3(TM * BB), 0, stream>>>(ws + PPTR_OFF, ws + ASENT_OFF,
                                                   ws + SSUM_OFF, ws + LSTAR_OFF,
                                                   tgt, out);
}